// Round 10
// baseline (193.744 us; speedup 1.0000x reference)
//
#include <hip/hip_runtime.h>

#define NF 8
#define NNS 4
#define NSL 7          // perm-partner slots per field
#define DIM_NS 100000
#define DIM_SEQ 1000
#define SEQ_LEN 50
#define DD 64
#define BB 16384
#define SCALE 4096.0f  // lift N(0,0.01) values out of fp8-e4m3 subnormal range
#define NB 16          // batch groups per chunk kind (pool-v2)
#define NKIND 32       // 4 fields x 4 slot-pairs x 2 dim-halves
#define CHUNK_U32 16000  // 1000 v x 16 m  (64,000 B LDS chunk)

typedef unsigned int u32;
typedef unsigned short u16;
typedef float floatx2 __attribute__((ext_vector_type(2)));

__device__ __forceinline__ u16 f2bf(float x) {
  u32 u = __float_as_uint(x);
  return (u16)((u + 0x7FFFu + ((u >> 16) & 1u)) >> 16);  // RNE
}

// ============ tier-1: two-phase v2 ============
// packed3: u32 at [kind][v][m]; kind=(f,sg,dh): bytes = fp8 {sA@D0, sA@D0+1,
// sB@D0, sB@D0+1}, sA=2sg, sB=2sg+1 (sB==7 -> 0), D0 = dh*32 + 2m.
__global__ __launch_bounds__(256) void pack3_kernel(const float* __restrict__ tseq,
                                                    u32* __restrict__ packed3) {
  const int id = blockIdx.x * 256 + threadIdx.x;  // 512,000
  const int m = id & 15;
  const int v = (id >> 4) % DIM_SEQ;
  const int kind = id / (16 * DIM_SEQ);
  const int dh = kind & 1, sg = (kind >> 1) & 3, f = kind >> 3;
  const int D0 = dh * 32 + 2 * m;
  const int sA = 2 * sg, sB = sA + 1;
  float a = tseq[((size_t)(f * NSL + sA) * DIM_SEQ + v) * DD + D0] * SCALE;
  float b = tseq[((size_t)(f * NSL + sA) * DIM_SEQ + v) * DD + D0 + 1] * SCALE;
  float c = 0.f, d = 0.f;
  if (sB < NSL) {
    c = tseq[((size_t)(f * NSL + sB) * DIM_SEQ + v) * DD + D0] * SCALE;
    d = tseq[((size_t)(f * NSL + sB) * DIM_SEQ + v) * DD + D0 + 1] * SCALE;
  }
  u32 r = __builtin_amdgcn_cvt_pk_fp8_f32(a, b, 0, false);
  r     = __builtin_amdgcn_cvt_pk_fp8_f32(c, d, r, true);
  packed3[id] = r;
}

// pool-v2: block = (kind, batch-group of 1024). 64KB LDS chunk -> 2 blocks/CU
// (32 waves/CU). Per wave-task (one b): one lane-vector idx load + bpermute
// distribution; quarter q handles indices 4k+q; 16 dim-lanes per quarter.
__global__ __launch_bounds__(1024, 8) void pool2_kernel(const u32* __restrict__ packed3,
                                                        const int* __restrict__ idx_seq,
                                                        u32* __restrict__ Ebuf) {
  __shared__ u32 chunk[CHUNK_U32];  // 64,000 B
  const int kind = blockIdx.x / NB, nb = blockIdx.x % NB;
  const int dh = kind & 1, sg = (kind >> 1) & 3, f = kind >> 3;

  {
    const uint4* src4 = reinterpret_cast<const uint4*>(packed3 + (size_t)kind * CHUNK_U32);
    uint4* dst4 = reinterpret_cast<uint4*>(chunk);
    for (int i = threadIdx.x; i < CHUNK_U32 / 4; i += 1024) dst4[i] = src4[i];
  }
  __syncthreads();

  const int W = threadIdx.x >> 6, lane = threadIdx.x & 63;
  const int q = lane >> 4, m = lane & 15;
  const int sA = 2 * sg, sB = sA + 1;
  const float inv = 1.0f / (50.0f * SCALE);
  const int b0 = nb * 1024 + W * 64;

  int my = (lane < SEQ_LEN) ? idx_seq[((size_t)f * BB + b0) * SEQ_LEN + lane] : 0;
  for (int e = 0; e < 64; ++e) {
    const int b = b0 + e;
    int myn = 0;
    if (e < 63 && lane < SEQ_LEN)
      myn = idx_seq[((size_t)f * BB + (b + 1)) * SEQ_LEN + lane];

    floatx2 accA = {0.f, 0.f}, accB = {0.f, 0.f};
#pragma unroll
    for (int k = 0; k < 12; ++k) {               // indices 0..47
      const int vi = __shfl(my, 4 * k + q, 64);  // ds_bpermute
      const u32 u = chunk[vi * 16 + m];
      accA += __builtin_amdgcn_cvt_pk_f32_fp8(u, false);  // sA @ D0, D0+1
      accB += __builtin_amdgcn_cvt_pk_f32_fp8(u, true);   // sB @ D0, D0+1
    }
    {  // tail indices 48,49 on quarters 0,1 (shfl hoisted: all lanes active)
      const int vi = __shfl(my, 48 + q, 64);
      if (q < 2) {
        const u32 u = chunk[vi * 16 + m];
        accA += __builtin_amdgcn_cvt_pk_f32_fp8(u, false);
        accB += __builtin_amdgcn_cvt_pk_f32_fp8(u, true);
      }
    }
    // reduce the 4 quarters
    accA.x += __shfl_xor(accA.x, 16, 64); accA.x += __shfl_xor(accA.x, 32, 64);
    accA.y += __shfl_xor(accA.y, 16, 64); accA.y += __shfl_xor(accA.y, 32, 64);
    accB.x += __shfl_xor(accB.x, 16, 64); accB.x += __shfl_xor(accB.x, 32, 64);
    accB.y += __shfl_xor(accB.y, 16, 64); accB.y += __shfl_xor(accB.y, 32, 64);

    if (q == 0) {  // lanes 0..15 hold final sums for dims D0, D0+1
      const u32 wA = (u32)f2bf(accA.x * inv) | ((u32)f2bf(accA.y * inv) << 16);
      Ebuf[((size_t)b * 28 + f * NSL + sA) * 32 + dh * 16 + m] = wA;
      if (sB < NSL) {
        const u32 wB = (u32)f2bf(accB.x * inv) | ((u32)f2bf(accB.y * inv) << 16);
        Ebuf[((size_t)b * 28 + f * NSL + sB) * 32 + dh * 16 + m] = wB;
      }
    }
    my = myn;
  }
}

// pair list: combinations(8, 2) in reference order
__device__ __constant__ int PAIR_A[28] = {0,0,0,0,0,0,0, 1,1,1,1,1,1, 2,2,2,2,2, 3,3,3,3, 4,4,4, 5,5, 6};
__device__ __constant__ int PAIR_C[28] = {1,2,3,4,5,6,7, 2,3,4,5,6,7, 3,4,5,6,7, 4,5,6,7, 5,6,7, 6,7, 7};

// Phase 2: one block per batch elem; wave w owns NS field w + seq field 4+w.
__global__ __launch_bounds__(256, 4) void dot_kernel(const float* __restrict__ tns,
                                                     const u32* __restrict__ Ebuf,
                                                     const int* __restrict__ idx_ns,
                                                     float* __restrict__ out) {
  __shared__ float e_lds[NF * NSL * DD];
  __shared__ float partial[4];
  const int lane = threadIdx.x & 63;
  const int w    = threadIdx.x >> 6;
  const int b    = blockIdx.x;
  const int d    = lane;

  float ns[NSL];
  {
    const int ia = idx_ns[w * BB + b];
#pragma unroll
    for (int sIt = 0; sIt < NSL; ++sIt) {
      ns[sIt] = tns[((size_t)(w * NSL + sIt) * DIM_NS + ia) * DD + d];
    }
  }
  const u16* Eh = (const u16*)Ebuf;
#pragma unroll
  for (int sIt = 0; sIt < NSL; ++sIt) {
    const u32 raw = Eh[((size_t)b * 28 + w * NSL + sIt) * DD + d];
    e_lds[((NNS + w) * NSL + sIt) * DD + d] = __uint_as_float(raw << 16);
  }
#pragma unroll
  for (int sIt = 0; sIt < NSL; ++sIt) e_lds[(w * NSL + sIt) * DD + d] = ns[sIt];

  __syncthreads();

  float r = 0.f;
#pragma unroll
  for (int p = 0; p < NSL; ++p) {
    const int pi = w * NSL + p;
    const int a = PAIR_A[pi];
    const int c = PAIR_C[pi];
    r += e_lds[(a * NSL + (c - 1)) * DD + d] * e_lds[(c * NSL + a) * DD + d];
  }
#pragma unroll
  for (int off = 32; off > 0; off >>= 1) r += __shfl_down(r, off);
  if (lane == 0) partial[w] = r;
  __syncthreads();
  if (threadIdx.x == 0) out[b] = partial[0] + partial[1] + partial[2] + partial[3];
}

// ============ tier-2: r8 fused path (benched 112.9 us) ============
__global__ __launch_bounds__(256) void pack_seq_kernel(const float* __restrict__ tseq,
                                                       uint2* __restrict__ packed) {
  int fv = blockIdx.x * 4 + (threadIdx.x >> 6);
  int d  = threadIdx.x & 63;
  int f = fv / DIM_SEQ, v = fv - f * DIM_SEQ;
  float h[8];
#pragma unroll
  for (int s = 0; s < NSL; ++s) {
    h[s] = tseq[((size_t)((f * NSL + s) * DIM_SEQ + v)) * DD + d] * SCALE;
  }
  h[7] = 0.f;
  u32 lo = __builtin_amdgcn_cvt_pk_fp8_f32(h[0], h[1], 0, false);
  lo     = __builtin_amdgcn_cvt_pk_fp8_f32(h[2], h[3], lo, true);
  u32 hi = __builtin_amdgcn_cvt_pk_fp8_f32(h[4], h[5], 0, false);
  hi     = __builtin_amdgcn_cvt_pk_fp8_f32(h[6], h[7], hi, true);
  uint2 val; val.x = lo; val.y = hi;
  packed[(size_t)fv * DD + d] = val;
}

template <bool PACKED>
__global__ __launch_bounds__(256, 4) void ffm_kernel(const float* __restrict__ tns,
                                                     const float* __restrict__ tseq,
                                                     const uint2* __restrict__ packed,
                                                     const int* __restrict__ idx_ns,
                                                     const int* __restrict__ idx_seq,
                                                     float* __restrict__ out) {
  __shared__ float e_lds[NF * NSL * DD];
  __shared__ float partial[4];
  const int lane = threadIdx.x & 63;
  const int w    = threadIdx.x >> 6;
  const int b    = blockIdx.x;
  const int d    = lane;

  float ns[NSL];
  {
    const int ia = idx_ns[w * BB + b];
#pragma unroll
    for (int s = 0; s < NSL; ++s) {
      ns[s] = tns[((size_t)(w * NSL + s) * DIM_NS + ia) * DD + d];
    }
  }
  int myidx = 0;
  if (lane < SEQ_LEN) myidx = idx_seq[(w * BB + b) * SEQ_LEN + lane];

  if (PACKED) {
    const int half = lane >> 5;
    const int m    = lane & 31;
    const char* tb = (const char*)packed + ((size_t)w * DIM_SEQ) * 512 + m * 16;
    floatx2 aA0 = {0.f, 0.f}, aA1 = aA0, aA2 = aA0, aA3 = aA0;
    floatx2 aB0 = aA0, aB1 = aA0, aB2 = aA0, aB3 = aA0;
#pragma unroll 5
    for (int k = 0; k < SEQ_LEN / 2; ++k) {
      const int i0 = __builtin_amdgcn_readlane(myidx, 2 * k);
      const int i1 = __builtin_amdgcn_readlane(myidx, 2 * k + 1);
      const int iv = half ? i1 : i0;
      const uint4 u = *reinterpret_cast<const uint4*>(tb + (size_t)iv * 512);
      aA0 += __builtin_amdgcn_cvt_pk_f32_fp8(u.x, false);
      aA1 += __builtin_amdgcn_cvt_pk_f32_fp8(u.x, true);
      aA2 += __builtin_amdgcn_cvt_pk_f32_fp8(u.y, false);
      aA3 += __builtin_amdgcn_cvt_pk_f32_fp8(u.y, true);
      aB0 += __builtin_amdgcn_cvt_pk_f32_fp8(u.z, false);
      aB1 += __builtin_amdgcn_cvt_pk_f32_fp8(u.z, true);
      aB2 += __builtin_amdgcn_cvt_pk_f32_fp8(u.w, false);
      aB3 += __builtin_amdgcn_cvt_pk_f32_fp8(u.w, true);
    }
    float sA[NSL] = {aA0.x, aA0.y, aA1.x, aA1.y, aA2.x, aA2.y, aA3.x};
    float sB[NSL] = {aB0.x, aB0.y, aB1.x, aB1.y, aB2.x, aB2.y, aB3.x};
    const float inv = 1.0f / (50.0f * SCALE);
#pragma unroll
    for (int s = 0; s < NSL; ++s) {
      const float tA = (sA[s] + __shfl_xor(sA[s], 32)) * inv;
      const float tB = (sB[s] + __shfl_xor(sB[s], 32)) * inv;
      if (half == 0) {
        float2 v2; v2.x = tA; v2.y = tB;
        *reinterpret_cast<float2*>(&e_lds[((NNS + w) * NSL + s) * DD + 2 * m]) = v2;
      }
    }
  } else {
    float acc[NSL];
#pragma unroll
    for (int s = 0; s < NSL; ++s) acc[s] = 0.f;
#pragma unroll 5
    for (int l = 0; l < SEQ_LEN; ++l) {
      const int iv = __builtin_amdgcn_readlane(myidx, l);
#pragma unroll
      for (int s = 0; s < NSL; ++s) {
        acc[s] += tseq[((size_t)(w * NSL + s) * DIM_SEQ + iv) * DD + d];
      }
    }
#pragma unroll
    for (int s = 0; s < NSL; ++s)
      e_lds[((NNS + w) * NSL + s) * DD + d] = acc[s] * (1.0f / 50.0f);
  }

#pragma unroll
  for (int s = 0; s < NSL; ++s) e_lds[(w * NSL + s) * DD + d] = ns[s];
  __syncthreads();

  float r = 0.f;
#pragma unroll
  for (int p = 0; p < NSL; ++p) {
    const int pi = w * NSL + p;
    const int a = PAIR_A[pi];
    const int c = PAIR_C[pi];
    r += e_lds[(a * NSL + (c - 1)) * DD + d] * e_lds[(c * NSL + a) * DD + d];
  }
#pragma unroll
  for (int off = 32; off > 0; off >>= 1) r += __shfl_down(r, off);
  if (lane == 0) partial[w] = r;
  __syncthreads();
  if (threadIdx.x == 0) out[b] = partial[0] + partial[1] + partial[2] + partial[3];
}

extern "C" void kernel_launch(void* const* d_in, const int* in_sizes, int n_in,
                              void* d_out, int out_size, void* d_ws, size_t ws_size,
                              hipStream_t stream) {
  const float* tns    = (const float*)d_in[0];
  const float* tseq   = (const float*)d_in[1];
  const int*   idx_ns = (const int*)d_in[2];
  const int*   idx_sq = (const int*)d_in[3];
  float* out = (float*)d_out;

  const size_t packed3_bytes = (size_t)NKIND * CHUNK_U32 * 4;   // 2,048,000
  const size_t E_bytes       = (size_t)BB * 28 * DD * 2;        // 58,720,256
  const size_t tier1_bytes   = packed3_bytes + E_bytes;

  if (ws_size >= tier1_bytes) {
    u32* packed3 = (u32*)d_ws;
    u32* Ebuf    = (u32*)((char*)d_ws + packed3_bytes);
    pack3_kernel<<<512000 / 256, 256, 0, stream>>>(tseq, packed3);
    pool2_kernel<<<NKIND * NB, 1024, 0, stream>>>(packed3, idx_sq, Ebuf);
    dot_kernel<<<BB, 256, 0, stream>>>(tns, Ebuf, idx_ns, out);
  } else if (ws_size >= packed3_bytes) {
    pack_seq_kernel<<<NNS * DIM_SEQ / 4, 256, 0, stream>>>(tseq, (uint2*)d_ws);
    ffm_kernel<true><<<BB, 256, 0, stream>>>(tns, tseq, (const uint2*)d_ws,
                                             idx_ns, idx_sq, out);
  } else {
    ffm_kernel<false><<<BB, 256, 0, stream>>>(tns, tseq, nullptr,
                                              idx_ns, idx_sq, out);
  }
}

// Round 11
// 113.107 us; speedup vs baseline: 1.7129x; 1.7129x over previous
//
#include <hip/hip_runtime.h>

#define NF 8
#define NNS 4
#define NSL 7          // perm-partner slots per field
#define DIM_NS 100000
#define DIM_SEQ 1000
#define SEQ_LEN 50
#define DD 64
#define BB 16384
#define SCALE 4096.0f  // lift N(0,0.01) values out of fp8-e4m3 subnormal range

typedef unsigned int u32;
typedef float floatx2 __attribute__((ext_vector_type(2)));

// packed layout: for (f, v): 64 d-entries, each 8 fp8 = slots 0..6 + zero pad.
// row (f,v) = 512 B contiguous; byte offset of (f,v,d) = ((f*1000+v)*64 + d) * 8
__global__ __launch_bounds__(256) void pack_seq_kernel(const float* __restrict__ tseq,
                                                       uint2* __restrict__ packed) {
  int fv = blockIdx.x * 4 + (threadIdx.x >> 6);   // 0..3999
  int d  = threadIdx.x & 63;
  int f = fv / DIM_SEQ, v = fv - f * DIM_SEQ;
  float h[8];
#pragma unroll
  for (int s = 0; s < NSL; ++s) {
    h[s] = tseq[((size_t)((f * NSL + s) * DIM_SEQ + v)) * DD + d] * SCALE;
  }
  h[7] = 0.f;
  u32 lo = __builtin_amdgcn_cvt_pk_fp8_f32(h[0], h[1], 0, false);
  lo     = __builtin_amdgcn_cvt_pk_fp8_f32(h[2], h[3], lo, true);
  u32 hi = __builtin_amdgcn_cvt_pk_fp8_f32(h[4], h[5], 0, false);
  hi     = __builtin_amdgcn_cvt_pk_fp8_f32(h[6], h[7], hi, true);
  uint2 val; val.x = lo; val.y = hi;
  packed[(size_t)fv * DD + d] = val;
}

// pair list: combinations(8, 2) in reference order
__device__ __constant__ int PAIR_A[28] = {0,0,0,0,0,0,0, 1,1,1,1,1,1, 2,2,2,2,2, 3,3,3,3, 4,4,4, 5,5, 6};
__device__ __constant__ int PAIR_C[28] = {1,2,3,4,5,6,7, 2,3,4,5,6,7, 3,4,5,6,7, 4,5,6,7, 5,6,7, 6,7, 7};

// One block per batch element. Wave w (0..3) owns NS field w and seq field 4+w.
// Gather: dwordx4 per lane, lane-halves serve two indices per instruction
// (lanes 0-31 -> index 2k, lanes 32-63 -> index 2k+1; each lane covers dims
// 2m, 2m+1 where m = lane&31). 25 VMEM instructions instead of 50.
template <bool PACKED>
__global__ __launch_bounds__(256, 4) void ffm_kernel(const float* __restrict__ tns,
                                                     const float* __restrict__ tseq,
                                                     const uint2* __restrict__ packed,
                                                     const int* __restrict__ idx_ns,
                                                     const int* __restrict__ idx_seq,
                                                     float* __restrict__ out) {
  __shared__ float e_lds[NF * NSL * DD];  // 14336 B: [field][slot][d]
  __shared__ float partial[4];

  const int lane = threadIdx.x & 63;
  const int w    = threadIdx.x >> 6;  // wave id 0..3
  const int b    = blockIdx.x;
  const int d    = lane;

  // ---- NS field w: issue 7 random HBM rows early; keep in regs during gathers ----
  float ns[NSL];
  {
    const int ia = idx_ns[w * BB + b];  // wave-uniform scalar load
#pragma unroll
    for (int s = 0; s < NSL; ++s) {
      ns[s] = tns[((size_t)(w * NSL + s) * DIM_NS + ia) * DD + d];
    }
  }

  // ---- seq field 4+w: mean-pool 50 gathered rows (fp8 packed) ----
  int myidx = 0;
  if (lane < SEQ_LEN) myidx = idx_seq[(w * BB + b) * SEQ_LEN + lane];

  if (PACKED) {
    const int half = lane >> 5;          // 0: even indices, 1: odd indices
    const int m    = lane & 31;          // dim pair id: dims 2m, 2m+1
    const char* tb = (const char*)packed + ((size_t)w * DIM_SEQ) * 512 + m * 16;

    floatx2 aA0 = {0.f, 0.f}, aA1 = aA0, aA2 = aA0, aA3 = aA0;  // dim 2m
    floatx2 aB0 = aA0, aB1 = aA0, aB2 = aA0, aB3 = aA0;          // dim 2m+1
#pragma unroll 5
    for (int k = 0; k < SEQ_LEN / 2; ++k) {
      const int i0 = __builtin_amdgcn_readlane(myidx, 2 * k);
      const int i1 = __builtin_amdgcn_readlane(myidx, 2 * k + 1);
      const int iv = half ? i1 : i0;
      const uint4 u = *reinterpret_cast<const uint4*>(tb + (size_t)iv * 512);
      aA0 += __builtin_amdgcn_cvt_pk_f32_fp8(u.x, false);  // dim 2m, slots 0,1
      aA1 += __builtin_amdgcn_cvt_pk_f32_fp8(u.x, true);   //          slots 2,3
      aA2 += __builtin_amdgcn_cvt_pk_f32_fp8(u.y, false);  //          slots 4,5
      aA3 += __builtin_amdgcn_cvt_pk_f32_fp8(u.y, true);   //          slot 6 + pad
      aB0 += __builtin_amdgcn_cvt_pk_f32_fp8(u.z, false);  // dim 2m+1
      aB1 += __builtin_amdgcn_cvt_pk_f32_fp8(u.z, true);
      aB2 += __builtin_amdgcn_cvt_pk_f32_fp8(u.w, false);
      aB3 += __builtin_amdgcn_cvt_pk_f32_fp8(u.w, true);
    }

    // merge even/odd halves (xor-32 swaps halves), write dims 2m, 2m+1
    float sA[NSL] = {aA0.x, aA0.y, aA1.x, aA1.y, aA2.x, aA2.y, aA3.x};
    float sB[NSL] = {aB0.x, aB0.y, aB1.x, aB1.y, aB2.x, aB2.y, aB3.x};
    const float inv = 1.0f / (50.0f * SCALE);
#pragma unroll
    for (int s = 0; s < NSL; ++s) {
      const float tA = (sA[s] + __shfl_xor(sA[s], 32)) * inv;
      const float tB = (sB[s] + __shfl_xor(sB[s], 32)) * inv;
      if (half == 0) {
        float2 v2; v2.x = tA; v2.y = tB;
        *reinterpret_cast<float2*>(&e_lds[((NNS + w) * NSL + s) * DD + 2 * m]) = v2;
      }
    }
  } else {
    float acc[NSL];
#pragma unroll
    for (int s = 0; s < NSL; ++s) acc[s] = 0.f;
#pragma unroll 5
    for (int l = 0; l < SEQ_LEN; ++l) {
      const int iv = __builtin_amdgcn_readlane(myidx, l);
#pragma unroll
      for (int s = 0; s < NSL; ++s) {
        acc[s] += tseq[((size_t)(w * NSL + s) * DIM_SEQ + iv) * DD + d];
      }
    }
#pragma unroll
    for (int s = 0; s < NSL; ++s)
      e_lds[((NNS + w) * NSL + s) * DD + d] = acc[s] * (1.0f / 50.0f);
  }

  // ---- NS rows to LDS (loads have had the whole gather loop to land) ----
#pragma unroll
  for (int s = 0; s < NSL; ++s) e_lds[(w * NSL + s) * DD + d] = ns[s];

  __syncthreads();

  // ---- 7 pair dots per wave from LDS ----
  // pair (a,c), a<c: a's slot for c is (c-1); c's slot for a is a.
  float r = 0.f;
#pragma unroll
  for (int p = 0; p < NSL; ++p) {
    const int pi = w * NSL + p;      // wave-uniform
    const int a  = PAIR_A[pi];
    const int c  = PAIR_C[pi];
    r += e_lds[(a * NSL + (c - 1)) * DD + d] * e_lds[(c * NSL + a) * DD + d];
  }

  // ---- reduce 64 lanes, then 4 waves ----
#pragma unroll
  for (int off = 32; off > 0; off >>= 1) r += __shfl_down(r, off);
  if (lane == 0) partial[w] = r;
  __syncthreads();
  if (threadIdx.x == 0) out[b] = partial[0] + partial[1] + partial[2] + partial[3];
}

extern "C" void kernel_launch(void* const* d_in, const int* in_sizes, int n_in,
                              void* d_out, int out_size, void* d_ws, size_t ws_size,
                              hipStream_t stream) {
  const float* tns    = (const float*)d_in[0];
  const float* tseq   = (const float*)d_in[1];
  const int*   idx_ns = (const int*)d_in[2];
  const int*   idx_sq = (const int*)d_in[3];
  float* out = (float*)d_out;

  const size_t packed_bytes = (size_t)NNS * DIM_SEQ * DD * 8;  // 2,048,000 B
  if (ws_size >= packed_bytes) {
    pack_seq_kernel<<<NNS * DIM_SEQ / 4, 256, 0, stream>>>(tseq, (uint2*)d_ws);
    ffm_kernel<true><<<BB, 256, 0, stream>>>(tns, tseq, (const uint2*)d_ws,
                                             idx_ns, idx_sq, out);
  } else {
    ffm_kernel<false><<<BB, 256, 0, stream>>>(tns, tseq, nullptr,
                                              idx_ns, idx_sq, out);
  }
}